// Round 1
// baseline (358.393 us; speedup 1.0000x reference)
//
#include <hip/hip_runtime.h>
#include <hip/hip_bf16.h>
#include <stdint.h>

#define L_SEQ  4096
#define H_DIM  512
#define N_ST   64
#define N_B    8
#define N_CH   16     // chunks per sequence
#define T_CH   256    // chunk length  (N_CH * T_CH == L_SEQ)
#define K_GEMM 1024
#define M_GEMM (N_B * L_SEQ)   // 32768

typedef float  f32x4  __attribute__((ext_vector_type(4)));
typedef __bf16 bf16x8 __attribute__((ext_vector_type(8)));
typedef unsigned short u16x8 __attribute__((ext_vector_type(8)));

// ---------------- K0: precompute A_bar, C*B_bar, A_bar^T ----------------
__global__ __launch_bounds__(256) void k_precompute(
    const float* __restrict__ A_log, const float* __restrict__ Bv,
    const float* __restrict__ C, const float* __restrict__ log_dt,
    const float* __restrict__ A_log_r, const float* __restrict__ B_r,
    const float* __restrict__ C_r,
    float* __restrict__ pA, float* __restrict__ pCB, float* __restrict__ pPW)
{
    int tid = blockIdx.x * 256 + threadIdx.x;      // 2*512*64 = 65536
    int n   = tid & 63;
    int h   = (tid >> 6) & 511;
    int dir = tid >> 15;
    float dt = expf(log_dt[h]);
    const float* Al = dir ? A_log_r : A_log;
    const float* Bp = dir ? B_r    : Bv;
    const float* Cp = dir ? C_r    : C;
    float eA = expf(Al[h * N_ST + n]);
    float Ab = expf(-dt * eA);
    float Bb = (1.0f - Ab) / eA * Bp[h * N_ST + n];
    pA[tid]  = Ab;                                  // tid == (dir*512+h)*64+n
    pCB[tid] = Cp[h * N_ST + n] * Bb;
    pPW[tid] = expf(-dt * eA * (float)T_CH);        // A_bar^T_CH exactly
}

// ---------------- Kw: W_bi f32 -> bf16 ----------------
__global__ __launch_bounds__(256) void k_convw(
    const float* __restrict__ W, __hip_bfloat16* __restrict__ Wbf)
{
    int tid = blockIdx.x * 256 + threadIdx.x;       // 512*1024
    Wbf[tid] = __float2bfloat16(W[tid]);
}

// ---------------- K1: per-chunk end states (zero init) ----------------
// chain = (dir, b, c, h), 4 lanes per chain (16 states each)
__global__ __launch_bounds__(256) void k_chunkstate(
    const float* __restrict__ u, const float* __restrict__ pA,
    float* __restrict__ S)
{
    int tid   = blockIdx.x * 256 + threadIdx.x;     // 524288
    int q     = tid & 3;
    int chain = tid >> 2;                           // 131072
    int h     = chain & 511;
    int rest  = chain >> 9;
    int c     = rest & 15; rest >>= 4;
    int b     = rest & 7;
    int dir   = rest >> 3;

    const float4* Ap = (const float4*)(pA + ((size_t)(dir * H_DIM + h)) * N_ST + q * 16);
    float A[16], x[16];
    #pragma unroll
    for (int i = 0; i < 4; ++i) {
        float4 a = Ap[i];
        A[4*i+0] = a.x; A[4*i+1] = a.y; A[4*i+2] = a.z; A[4*i+3] = a.w;
        x[4*i+0] = 0.f; x[4*i+1] = 0.f; x[4*i+2] = 0.f; x[4*i+3] = 0.f;
    }

    int s0     = c * T_CH;
    int l0     = dir ? (L_SEQ - 1 - s0) : s0;
    int stride = dir ? -H_DIM : H_DIM;
    int idx    = (b * L_SEQ + l0) * H_DIM + h;

    float uv = u[idx];
    #pragma unroll 2
    for (int j = 0; j < T_CH; ++j) {
        float cur = uv;
        idx += stride;
        uv = u[(j == T_CH - 1) ? 0 : idx];   // avoid OOB prefetch on last iter
        #pragma unroll
        for (int i = 0; i < 16; ++i) x[i] = fmaf(A[i], x[i], cur);
    }

    float4* Sp = (float4*)(S + ((((size_t)dir * N_CH + c) * N_B + b) * H_DIM + h) * N_ST + q * 16);
    #pragma unroll
    for (int i = 0; i < 4; ++i) {
        float4 v; v.x = x[4*i+0]; v.y = x[4*i+1]; v.z = x[4*i+2]; v.w = x[4*i+3];
        Sp[i] = v;
    }
}

// ---------------- K2: inter-chunk scan (in place: S -> incoming states) ----------------
__global__ __launch_bounds__(256) void k_chunkscan(
    const float* __restrict__ pPW, float* __restrict__ S)
{
    int tid = blockIdx.x * 256 + threadIdx.x;       // 524288 = 2*8*512*64
    int n   = tid & 63;
    int h   = (tid >> 6) & 511;
    int b   = (tid >> 15) & 7;
    int dir = tid >> 18;
    float pw = pPW[((size_t)(dir * H_DIM + h)) * N_ST + n];
    float X = 0.f;
    for (int c = 0; c < N_CH; ++c) {
        size_t a = ((((size_t)dir * N_CH + c) * N_B + b) * H_DIM + h) * N_ST + n;
        float tmp = S[a];
        S[a] = X;                 // incoming state for chunk c
        X = fmaf(pw, X, tmp);
    }
}

// ---------------- K3: full scan + output (bf16 ycat) ----------------
__global__ __launch_bounds__(256) void k_scanout(
    const float* __restrict__ u, const float* __restrict__ pA,
    const float* __restrict__ pCB, const float* __restrict__ Dv,
    const float* __restrict__ S, __hip_bfloat16* __restrict__ yc)
{
    int tid   = blockIdx.x * 256 + threadIdx.x;
    int q     = tid & 3;
    int chain = tid >> 2;
    int h     = chain & 511;
    int rest  = chain >> 9;
    int c     = rest & 15; rest >>= 4;
    int b     = rest & 7;
    int dir   = rest >> 3;

    const float4* Ap  = (const float4*)(pA  + ((size_t)(dir * H_DIM + h)) * N_ST + q * 16);
    const float4* CBp = (const float4*)(pCB + ((size_t)(dir * H_DIM + h)) * N_ST + q * 16);
    const float4* Sp  = (const float4*)(S + ((((size_t)dir * N_CH + c) * N_B + b) * H_DIM + h) * N_ST + q * 16);

    float A[16], CB[16], x[16];
    #pragma unroll
    for (int i = 0; i < 4; ++i) {
        float4 a = Ap[i], cb = CBp[i], xs = Sp[i];
        A[4*i+0]=a.x;  A[4*i+1]=a.y;  A[4*i+2]=a.z;  A[4*i+3]=a.w;
        CB[4*i+0]=cb.x; CB[4*i+1]=cb.y; CB[4*i+2]=cb.z; CB[4*i+3]=cb.w;
        x[4*i+0]=xs.x; x[4*i+1]=xs.y; x[4*i+2]=xs.z; x[4*i+3]=xs.w;
    }
    float Dh = Dv[h];

    int s0      = c * T_CH;
    int l0      = dir ? (L_SEQ - 1 - s0) : s0;
    int stride  = dir ? -H_DIM : H_DIM;
    long long ostride = dir ? -(long long)(2 * H_DIM) : (long long)(2 * H_DIM);
    int idx     = (b * L_SEQ + l0) * H_DIM + h;
    long long oidx = (long long)(b * L_SEQ + l0) * (2 * H_DIM) + dir * H_DIM + h;

    float uv = u[idx];
    #pragma unroll 2
    for (int j = 0; j < T_CH; ++j) {
        float cur = uv;
        idx += stride;
        uv = u[(j == T_CH - 1) ? 0 : idx];
        float p0 = 0.f, p1 = 0.f, p2 = 0.f, p3 = 0.f;
        #pragma unroll
        for (int i = 0; i < 4; ++i) {
            x[4*i+0] = fmaf(A[4*i+0], x[4*i+0], cur);
            x[4*i+1] = fmaf(A[4*i+1], x[4*i+1], cur);
            x[4*i+2] = fmaf(A[4*i+2], x[4*i+2], cur);
            x[4*i+3] = fmaf(A[4*i+3], x[4*i+3], cur);
            p0 = fmaf(CB[4*i+0], x[4*i+0], p0);
            p1 = fmaf(CB[4*i+1], x[4*i+1], p1);
            p2 = fmaf(CB[4*i+2], x[4*i+2], p2);
            p3 = fmaf(CB[4*i+3], x[4*i+3], p3);
        }
        float sum = (p0 + p1) + (p2 + p3);
        sum += __shfl_xor(sum, 1);
        sum += __shfl_xor(sum, 2);
        if (q == 0) yc[oidx] = __float2bfloat16(sum + Dh * cur);
        oidx += ostride;
    }
}

// ---------------- K4: out = ycat(bf16) @ W(bf16)^T + bias, f32 out ----------------
// A: [32768,1024] row-major, B: [512,1024] row-major (B^T GEMM), out: [32768,512]
__global__ __launch_bounds__(256) void k_gemm(
    const __hip_bfloat16* __restrict__ A, const __hip_bfloat16* __restrict__ B,
    const float* __restrict__ bias, float* __restrict__ out)
{
    __shared__ __hip_bfloat16 As[128][32];
    __shared__ __hip_bfloat16 Bs[128][32];
    int t  = threadIdx.x;
    int l  = t & 63, w = t >> 6;
    int lr = l & 15, lg = l >> 4;
    int mBase = blockIdx.y * 128;
    int nBase = blockIdx.x * 128;
    int wr = (w >> 1) * 64, wc = (w & 1) * 64;

    f32x4 acc[4][4] = {};

    for (int kt = 0; kt < K_GEMM; kt += 32) {
        __syncthreads();
        #pragma unroll
        for (int i = 0; i < 2; ++i) {
            int seg = t + i * 256;        // 0..511
            int row = seg >> 2;           // 0..127
            int kb  = (seg & 3) * 8;      // 0,8,16,24
            *(u16x8*)&As[row][kb] = *(const u16x8*)&A[(size_t)(mBase + row) * K_GEMM + kt + kb];
            *(u16x8*)&Bs[row][kb] = *(const u16x8*)&B[(size_t)(nBase + row) * K_GEMM + kt + kb];
        }
        __syncthreads();
        bf16x8 af[4], bfv[4];
        #pragma unroll
        for (int m = 0; m < 4; ++m) af[m]  = *(const bf16x8*)&As[wr + m * 16 + lr][lg * 8];
        #pragma unroll
        for (int n = 0; n < 4; ++n) bfv[n] = *(const bf16x8*)&Bs[wc + n * 16 + lr][lg * 8];
        #pragma unroll
        for (int m = 0; m < 4; ++m)
            #pragma unroll
            for (int n = 0; n < 4; ++n)
                acc[m][n] = __builtin_amdgcn_mfma_f32_16x16x32_bf16(af[m], bfv[n], acc[m][n], 0, 0, 0);
    }

    #pragma unroll
    for (int n = 0; n < 4; ++n) {
        int colg = nBase + wc + n * 16 + lr;
        float bv = bias[colg];
        #pragma unroll
        for (int m = 0; m < 4; ++m) {
            int rowg = mBase + wr + m * 16 + lg * 4;
            #pragma unroll
            for (int r = 0; r < 4; ++r)
                out[(size_t)(rowg + r) * H_DIM + colg] = acc[m][n][r] + bv;
        }
    }
}

extern "C" void kernel_launch(void* const* d_in, const int* in_sizes, int n_in,
                              void* d_out, int out_size, void* d_ws, size_t ws_size,
                              hipStream_t stream)
{
    const float* u       = (const float*)d_in[0];
    const float* A_log   = (const float*)d_in[1];
    const float* Bv      = (const float*)d_in[2];
    const float* C       = (const float*)d_in[3];
    const float* D       = (const float*)d_in[4];
    const float* log_dt  = (const float*)d_in[5];
    const float* A_log_r = (const float*)d_in[6];
    const float* B_r     = (const float*)d_in[7];
    const float* C_r     = (const float*)d_in[8];
    const float* W_bi    = (const float*)d_in[9];
    const float* b_bi    = (const float*)d_in[10];
    float* out = (float*)d_out;

    char* ws = (char*)d_ws;
    float* pA  = (float*)(ws);                       // 65536 f
    float* pCB = (float*)(ws + 262144);              // 65536 f
    float* pPW = (float*)(ws + 524288);              // 65536 f
    float* S   = (float*)(ws + 786432);              // 8388608 f (32 MB)
    __hip_bfloat16* yc  = (__hip_bfloat16*)(ws + 786432 + 33554432);            // 64 MB
    __hip_bfloat16* Wbf = (__hip_bfloat16*)(ws + 786432 + 33554432 + 67108864); // 1 MB

    k_precompute<<<256,  256, 0, stream>>>(A_log, Bv, C, log_dt, A_log_r, B_r, C_r, pA, pCB, pPW);
    k_convw     <<<2048, 256, 0, stream>>>(W_bi, Wbf);
    k_chunkstate<<<2048, 256, 0, stream>>>(u, pA, S);
    k_chunkscan <<<2048, 256, 0, stream>>>(pPW, S);
    k_scanout   <<<2048, 256, 0, stream>>>(u, pA, pCB, D, S, yc);
    dim3 g(4, 256);
    k_gemm<<<g, 256, 0, stream>>>(yc, Wbf, b_bi, out);
}

// Round 2
// 296.149 us; speedup vs baseline: 1.2102x; 1.2102x over previous
//
#include <hip/hip_runtime.h>
#include <hip/hip_bf16.h>
#include <stdint.h>

#define L_SEQ  4096
#define H_DIM  512
#define N_ST   64
#define N_B    8
#define N_CH   16     // chunks per sequence
#define T_CH   256    // chunk length  (N_CH * T_CH == L_SEQ)
#define K_GEMM 1024

typedef float  f32x4  __attribute__((ext_vector_type(4)));
typedef __bf16 bf16x8 __attribute__((ext_vector_type(8)));
typedef unsigned short u16x8 __attribute__((ext_vector_type(8)));

// ---------------- K0: precompute A_bar, C*B_bar, A_bar^T ----------------
__global__ __launch_bounds__(256) void k_precompute(
    const float* __restrict__ A_log, const float* __restrict__ Bv,
    const float* __restrict__ C, const float* __restrict__ log_dt,
    const float* __restrict__ A_log_r, const float* __restrict__ B_r,
    const float* __restrict__ C_r,
    float* __restrict__ pA, float* __restrict__ pCB, float* __restrict__ pPW)
{
    int tid = blockIdx.x * 256 + threadIdx.x;      // 2*512*64 = 65536
    int n   = tid & 63;
    int h   = (tid >> 6) & 511;
    int dir = tid >> 15;
    float dt = expf(log_dt[h]);
    const float* Al = dir ? A_log_r : A_log;
    const float* Bp = dir ? B_r    : Bv;
    const float* Cp = dir ? C_r    : C;
    float eA = expf(Al[h * N_ST + n]);
    float Ab = expf(-dt * eA);
    float Bb = (1.0f - Ab) / eA * Bp[h * N_ST + n];
    pA[tid]  = Ab;                                  // tid == (dir*512+h)*64+n
    pCB[tid] = Cp[h * N_ST + n] * Bb;
    pPW[tid] = expf(-dt * eA * (float)T_CH);        // A_bar^T_CH exactly
}

// ---------------- Kw: W_bi f32 -> bf16 ----------------
__global__ __launch_bounds__(256) void k_convw(
    const float* __restrict__ W, __hip_bfloat16* __restrict__ Wbf)
{
    int tid = blockIdx.x * 256 + threadIdx.x;       // 512*1024
    Wbf[tid] = __float2bfloat16(W[tid]);
}

// ---------------- K1: per-chunk end states (zero init) ----------------
// chain = (dir, b, c, h), 2 lanes per chain (32 states each), h in low bits
__global__ __launch_bounds__(256) void k_chunkstate(
    const float* __restrict__ u, const float* __restrict__ pA,
    float* __restrict__ S)
{
    int tid = blockIdx.x * 256 + threadIdx.x;       // 262144
    int q   = tid & 1;
    int h   = (tid >> 1) & 511;
    int c   = (tid >> 10) & 15;
    int b   = (tid >> 14) & 7;
    int dir = tid >> 17;

    const f32x4* Ap = (const f32x4*)(pA + (size_t)(dir * H_DIM + h) * N_ST + q * 32);
    float A[32], x[32];
    #pragma unroll
    for (int i = 0; i < 8; ++i) {
        f32x4 a = Ap[i];
        A[4*i+0] = a[0]; A[4*i+1] = a[1]; A[4*i+2] = a[2]; A[4*i+3] = a[3];
        x[4*i+0] = 0.f;  x[4*i+1] = 0.f;  x[4*i+2] = 0.f;  x[4*i+3] = 0.f;
    }

    int l0     = dir ? (L_SEQ - 1 - c * T_CH) : c * T_CH;
    int stride = dir ? -H_DIM : H_DIM;
    const float* up = u + (size_t)(b * L_SEQ + l0) * H_DIM + h;

    float uv = *up;
    #pragma unroll 4
    for (int j = 0; j < T_CH - 1; ++j) {
        float cur = uv;
        up += stride;
        uv = *up;
        #pragma unroll
        for (int i = 0; i < 32; ++i) x[i] = fmaf(A[i], x[i], cur);
    }
    #pragma unroll
    for (int i = 0; i < 32; ++i) x[i] = fmaf(A[i], x[i], uv);

    f32x4* Sp = (f32x4*)(S + ((((size_t)dir * N_CH + c) * N_B + b) * H_DIM + h) * N_ST + q * 32);
    #pragma unroll
    for (int i = 0; i < 8; ++i) {
        f32x4 v; v[0] = x[4*i+0]; v[1] = x[4*i+1]; v[2] = x[4*i+2]; v[3] = x[4*i+3];
        Sp[i] = v;
    }
}

// ---------------- K2: inter-chunk scan (in place: S -> incoming states) ----------------
__global__ __launch_bounds__(256) void k_chunkscan(
    const float* __restrict__ pPW, float* __restrict__ S)
{
    int tid = blockIdx.x * 256 + threadIdx.x;       // 524288 = 2*8*512*64
    int n   = tid & 63;
    int h   = (tid >> 6) & 511;
    int b   = (tid >> 15) & 7;
    int dir = tid >> 18;
    float pw = pPW[((size_t)(dir * H_DIM + h)) * N_ST + n];
    float X = 0.f;
    for (int c = 0; c < N_CH; ++c) {
        size_t a = ((((size_t)dir * N_CH + c) * N_B + b) * H_DIM + h) * N_ST + n;
        float tmp = S[a];
        S[a] = X;                 // incoming state for chunk c
        X = fmaf(pw, X, tmp);
    }
}

// ---------------- K3: full scan + output (bf16 ycat) ----------------
__global__ __launch_bounds__(256) void k_scanout(
    const float* __restrict__ u, const float* __restrict__ pA,
    const float* __restrict__ pCB, const float* __restrict__ Dv,
    const float* __restrict__ S, __hip_bfloat16* __restrict__ yc)
{
    int tid = blockIdx.x * 256 + threadIdx.x;       // 262144
    int q   = tid & 1;
    int h   = (tid >> 1) & 511;
    int c   = (tid >> 10) & 15;
    int b   = (tid >> 14) & 7;
    int dir = tid >> 17;

    const f32x4* Ap  = (const f32x4*)(pA  + (size_t)(dir * H_DIM + h) * N_ST + q * 32);
    const f32x4* CBp = (const f32x4*)(pCB + (size_t)(dir * H_DIM + h) * N_ST + q * 32);
    const f32x4* Sp  = (const f32x4*)(S + ((((size_t)dir * N_CH + c) * N_B + b) * H_DIM + h) * N_ST + q * 32);

    float A[32], CB[32], x[32];
    #pragma unroll
    for (int i = 0; i < 8; ++i) {
        f32x4 a = Ap[i], cb = CBp[i], xs = Sp[i];
        A[4*i+0]=a[0];  A[4*i+1]=a[1];  A[4*i+2]=a[2];  A[4*i+3]=a[3];
        CB[4*i+0]=cb[0]; CB[4*i+1]=cb[1]; CB[4*i+2]=cb[2]; CB[4*i+3]=cb[3];
        x[4*i+0]=xs[0]; x[4*i+1]=xs[1]; x[4*i+2]=xs[2]; x[4*i+3]=xs[3];
    }
    float Dh = Dv[h];

    int l0     = dir ? (L_SEQ - 1 - c * T_CH) : c * T_CH;
    int stride = dir ? -H_DIM : H_DIM;
    int ostr   = dir ? -(2 * H_DIM) : (2 * H_DIM);
    const float* up = u + (size_t)(b * L_SEQ + l0) * H_DIM + h;
    __hip_bfloat16* yp = yc + (size_t)(b * L_SEQ + l0) * (2 * H_DIM) + dir * H_DIM + h;

    float uv = *up;
    #pragma unroll 4
    for (int j = 0; j < T_CH; ++j) {
        float cur = uv;
        if (j < T_CH - 1) { up += stride; uv = *up; }
        float p0 = 0.f, p1 = 0.f, p2 = 0.f, p3 = 0.f;
        #pragma unroll
        for (int i = 0; i < 8; ++i) {
            x[4*i+0] = fmaf(A[4*i+0], x[4*i+0], cur);
            x[4*i+1] = fmaf(A[4*i+1], x[4*i+1], cur);
            x[4*i+2] = fmaf(A[4*i+2], x[4*i+2], cur);
            x[4*i+3] = fmaf(A[4*i+3], x[4*i+3], cur);
            p0 = fmaf(CB[4*i+0], x[4*i+0], p0);
            p1 = fmaf(CB[4*i+1], x[4*i+1], p1);
            p2 = fmaf(CB[4*i+2], x[4*i+2], p2);
            p3 = fmaf(CB[4*i+3], x[4*i+3], p3);
        }
        float s = (p0 + p1) + (p2 + p3);
        s += __shfl_xor(s, 1);                       // pair (q=0,q=1) -> full 64-state sum
        // both lanes of the pair store the identical value to the identical
        // address: no predication needed, deterministic result.
        *yp = __float2bfloat16(fmaf(Dh, cur, s));
        yp += ostr;
    }
}

// ---------------- K4: out = ycat(bf16) @ W(bf16)^T + bias, f32 out ----------------
// A: [32768,1024] row-major, B: [512,1024] row-major (B^T GEMM), out: [32768,512]
// LDS rows padded 32 -> 40 cols (80B) so 16-lane column reads spread across
// 8 bank groups (2-way conflict = free) instead of 8-way.
#define LPAD 40
__global__ __launch_bounds__(256) void k_gemm(
    const __hip_bfloat16* __restrict__ A, const __hip_bfloat16* __restrict__ B,
    const float* __restrict__ bias, float* __restrict__ out)
{
    __shared__ __hip_bfloat16 As[128][LPAD];
    __shared__ __hip_bfloat16 Bs[128][LPAD];
    int t  = threadIdx.x;
    int l  = t & 63, w = t >> 6;
    int lr = l & 15, lg = l >> 4;
    int mBase = blockIdx.y * 128;
    int nBase = blockIdx.x * 128;
    int wr = (w >> 1) * 64, wc = (w & 1) * 64;

    f32x4 acc[4][4] = {};

    for (int kt = 0; kt < K_GEMM; kt += 32) {
        __syncthreads();
        #pragma unroll
        for (int i = 0; i < 2; ++i) {
            int seg = t + i * 256;        // 0..511
            int row = seg >> 2;           // 0..127
            int kb  = (seg & 3) * 8;      // 0,8,16,24
            *(u16x8*)&As[row][kb] = *(const u16x8*)&A[(size_t)(mBase + row) * K_GEMM + kt + kb];
            *(u16x8*)&Bs[row][kb] = *(const u16x8*)&B[(size_t)(nBase + row) * K_GEMM + kt + kb];
        }
        __syncthreads();
        bf16x8 af[4], bfv[4];
        #pragma unroll
        for (int m = 0; m < 4; ++m) af[m]  = *(const bf16x8*)&As[wr + m * 16 + lr][lg * 8];
        #pragma unroll
        for (int n = 0; n < 4; ++n) bfv[n] = *(const bf16x8*)&Bs[wc + n * 16 + lr][lg * 8];
        #pragma unroll
        for (int m = 0; m < 4; ++m)
            #pragma unroll
            for (int n = 0; n < 4; ++n)
                acc[m][n] = __builtin_amdgcn_mfma_f32_16x16x32_bf16(af[m], bfv[n], acc[m][n], 0, 0, 0);
    }

    #pragma unroll
    for (int n = 0; n < 4; ++n) {
        int colg = nBase + wc + n * 16 + lr;
        float bv = bias[colg];
        #pragma unroll
        for (int m = 0; m < 4; ++m) {
            int rowg = mBase + wr + m * 16 + lg * 4;
            #pragma unroll
            for (int r = 0; r < 4; ++r)
                out[(size_t)(rowg + r) * H_DIM + colg] = acc[m][n][r] + bv;
        }
    }
}

extern "C" void kernel_launch(void* const* d_in, const int* in_sizes, int n_in,
                              void* d_out, int out_size, void* d_ws, size_t ws_size,
                              hipStream_t stream)
{
    const float* u       = (const float*)d_in[0];
    const float* A_log   = (const float*)d_in[1];
    const float* Bv      = (const float*)d_in[2];
    const float* C       = (const float*)d_in[3];
    const float* D       = (const float*)d_in[4];
    const float* log_dt  = (const float*)d_in[5];
    const float* A_log_r = (const float*)d_in[6];
    const float* B_r     = (const float*)d_in[7];
    const float* C_r     = (const float*)d_in[8];
    const float* W_bi    = (const float*)d_in[9];
    const float* b_bi    = (const float*)d_in[10];
    float* out = (float*)d_out;

    char* ws = (char*)d_ws;
    float* pA  = (float*)(ws);                       // 65536 f
    float* pCB = (float*)(ws + 262144);              // 65536 f
    float* pPW = (float*)(ws + 524288);              // 65536 f
    float* S   = (float*)(ws + 786432);              // 8388608 f (32 MB)
    __hip_bfloat16* yc  = (__hip_bfloat16*)(ws + 786432 + 33554432);            // 64 MB
    __hip_bfloat16* Wbf = (__hip_bfloat16*)(ws + 786432 + 33554432 + 67108864); // 1 MB

    k_precompute<<<256,  256, 0, stream>>>(A_log, Bv, C, log_dt, A_log_r, B_r, C_r, pA, pCB, pPW);
    k_convw     <<<2048, 256, 0, stream>>>(W_bi, Wbf);
    k_chunkstate<<<1024, 256, 0, stream>>>(u, pA, S);
    k_chunkscan <<<2048, 256, 0, stream>>>(pPW, S);
    k_scanout   <<<1024, 256, 0, stream>>>(u, pA, pCB, D, S, yc);
    dim3 g(4, 256);
    k_gemm<<<g, 256, 0, stream>>>(yc, Wbf, b_bi, out);
}

// Round 3
// 287.916 us; speedup vs baseline: 1.2448x; 1.0286x over previous
//
#include <hip/hip_runtime.h>
#include <hip/hip_bf16.h>
#include <stdint.h>

#define L_SEQ  4096
#define H_DIM  512
#define N_ST   64
#define N_B    8
#define N_CH   16     // chunks per sequence
#define T_CH   256    // chunk length  (N_CH * T_CH == L_SEQ)
#define K_GEMM 1024

typedef float  f32x4  __attribute__((ext_vector_type(4)));
typedef __bf16 bf16x8 __attribute__((ext_vector_type(8)));

// ---------------- K0: precompute A_bar, C*B_bar, A_bar^T ----------------
__global__ __launch_bounds__(256) void k_precompute(
    const float* __restrict__ A_log, const float* __restrict__ Bv,
    const float* __restrict__ C, const float* __restrict__ log_dt,
    const float* __restrict__ A_log_r, const float* __restrict__ B_r,
    const float* __restrict__ C_r,
    float* __restrict__ pA, float* __restrict__ pCB, float* __restrict__ pPW)
{
    int tid = blockIdx.x * 256 + threadIdx.x;      // 2*512*64 = 65536
    int n   = tid & 63;
    int h   = (tid >> 6) & 511;
    int dir = tid >> 15;
    float dt = expf(log_dt[h]);
    const float* Al = dir ? A_log_r : A_log;
    const float* Bp = dir ? B_r    : Bv;
    const float* Cp = dir ? C_r    : C;
    float eA = expf(Al[h * N_ST + n]);
    float Ab = expf(-dt * eA);
    float Bb = (1.0f - Ab) / eA * Bp[h * N_ST + n];
    pA[tid]  = Ab;                                  // tid == (dir*512+h)*64+n
    pCB[tid] = Cp[h * N_ST + n] * Bb;
    pPW[tid] = expf(-dt * eA * (float)T_CH);        // A_bar^T_CH exactly
}

// ---------------- Kw: W_bi f32 -> bf16 ----------------
__global__ __launch_bounds__(256) void k_convw(
    const float* __restrict__ W, __hip_bfloat16* __restrict__ Wbf)
{
    int tid = blockIdx.x * 256 + threadIdx.x;       // 512*1024
    Wbf[tid] = __float2bfloat16(W[tid]);
}

// ---------------- K1: per-chunk end states (zero init) ----------------
// chain = (dir, b, c, h), 2 lanes per chain (32 states each), h in low bits
#define PF1 8
__global__ __launch_bounds__(256, 4) void k_chunkstate(
    const float* __restrict__ u, const float* __restrict__ pA,
    float* __restrict__ S)
{
    int tid = blockIdx.x * 256 + threadIdx.x;       // 262144
    int q   = tid & 1;
    int h   = (tid >> 1) & 511;
    int c   = (tid >> 10) & 15;
    int b   = (tid >> 14) & 7;
    int dir = tid >> 17;

    const f32x4* Ap = (const f32x4*)(pA + (size_t)(dir * H_DIM + h) * N_ST + q * 32);
    float A[32], x[32];
    #pragma unroll
    for (int i = 0; i < 8; ++i) {
        f32x4 a = Ap[i];
        A[4*i+0] = a[0]; A[4*i+1] = a[1]; A[4*i+2] = a[2]; A[4*i+3] = a[3];
        x[4*i+0] = 0.f;  x[4*i+1] = 0.f;  x[4*i+2] = 0.f;  x[4*i+3] = 0.f;
    }

    int l0     = dir ? (L_SEQ - 1 - c * T_CH) : c * T_CH;
    int stride = dir ? -H_DIM : H_DIM;
    const float* up = u + (size_t)(b * L_SEQ + l0) * H_DIM + h;

    float buf[PF1];
    #pragma unroll
    for (int k = 0; k < PF1; ++k) buf[k] = up[k * stride];

    for (int blk = 0; blk < T_CH / PF1 - 1; ++blk) {
        const float* nup = up + PF1 * stride;
        float nbuf[PF1];
        #pragma unroll
        for (int k = 0; k < PF1; ++k) nbuf[k] = nup[k * stride];
        #pragma unroll
        for (int k = 0; k < PF1; ++k) {
            float cur = buf[k];
            #pragma unroll
            for (int i = 0; i < 32; ++i) x[i] = fmaf(A[i], x[i], cur);
        }
        #pragma unroll
        for (int k = 0; k < PF1; ++k) buf[k] = nbuf[k];
        up = nup;
    }
    #pragma unroll
    for (int k = 0; k < PF1; ++k) {
        float cur = buf[k];
        #pragma unroll
        for (int i = 0; i < 32; ++i) x[i] = fmaf(A[i], x[i], cur);
    }

    f32x4* Sp = (f32x4*)(S + ((((size_t)dir * N_CH + c) * N_B + b) * H_DIM + h) * N_ST + q * 32);
    #pragma unroll
    for (int i = 0; i < 8; ++i) {
        f32x4 v; v[0] = x[4*i+0]; v[1] = x[4*i+1]; v[2] = x[4*i+2]; v[3] = x[4*i+3];
        Sp[i] = v;
    }
}

// ---------------- K2: inter-chunk scan (in place: S -> incoming states) ----------------
__global__ __launch_bounds__(256) void k_chunkscan(
    const float* __restrict__ pPW, float* __restrict__ S)
{
    int tid = blockIdx.x * 256 + threadIdx.x;       // 524288 = 2*8*512*64
    int n   = tid & 63;
    int h   = (tid >> 6) & 511;
    int b   = (tid >> 15) & 7;
    int dir = tid >> 18;
    float pw = pPW[((size_t)(dir * H_DIM + h)) * N_ST + n];
    float X = 0.f;
    for (int c = 0; c < N_CH; ++c) {
        size_t a = ((((size_t)dir * N_CH + c) * N_B + b) * H_DIM + h) * N_ST + n;
        float tmp = S[a];
        S[a] = X;                 // incoming state for chunk c
        X = fmaf(pw, X, tmp);
    }
}

// ---------------- K3: full scan + output (bf16 ycat) ----------------
#define PF3 4
__global__ __launch_bounds__(256, 4) void k_scanout(
    const float* __restrict__ u, const float* __restrict__ pA,
    const float* __restrict__ pCB, const float* __restrict__ Dv,
    const float* __restrict__ S, __hip_bfloat16* __restrict__ yc)
{
    int tid = blockIdx.x * 256 + threadIdx.x;       // 262144
    int q   = tid & 1;
    int h   = (tid >> 1) & 511;
    int c   = (tid >> 10) & 15;
    int b   = (tid >> 14) & 7;
    int dir = tid >> 17;

    const f32x4* Ap  = (const f32x4*)(pA  + (size_t)(dir * H_DIM + h) * N_ST + q * 32);
    const f32x4* CBp = (const f32x4*)(pCB + (size_t)(dir * H_DIM + h) * N_ST + q * 32);
    const f32x4* Sp  = (const f32x4*)(S + ((((size_t)dir * N_CH + c) * N_B + b) * H_DIM + h) * N_ST + q * 32);

    float A[32], CB[32], x[32];
    #pragma unroll
    for (int i = 0; i < 8; ++i) {
        f32x4 a = Ap[i], cb = CBp[i], xs = Sp[i];
        A[4*i+0]=a[0];  A[4*i+1]=a[1];  A[4*i+2]=a[2];  A[4*i+3]=a[3];
        CB[4*i+0]=cb[0]; CB[4*i+1]=cb[1]; CB[4*i+2]=cb[2]; CB[4*i+3]=cb[3];
        x[4*i+0]=xs[0]; x[4*i+1]=xs[1]; x[4*i+2]=xs[2]; x[4*i+3]=xs[3];
    }
    float Dh = Dv[h];

    int l0     = dir ? (L_SEQ - 1 - c * T_CH) : c * T_CH;
    int stride = dir ? -H_DIM : H_DIM;
    int ostr   = dir ? -(2 * H_DIM) : (2 * H_DIM);
    const float* up = u + (size_t)(b * L_SEQ + l0) * H_DIM + h;
    __hip_bfloat16* yp = yc + (size_t)(b * L_SEQ + l0) * (2 * H_DIM) + dir * H_DIM + h;

    float buf[PF3];
    #pragma unroll
    for (int k = 0; k < PF3; ++k) buf[k] = up[k * stride];

    for (int blk = 0; blk < T_CH / PF3; ++blk) {
        const float* nup = up + PF3 * stride;
        float nbuf[PF3];
        if (blk < T_CH / PF3 - 1) {
            #pragma unroll
            for (int k = 0; k < PF3; ++k) nbuf[k] = nup[k * stride];
        }
        #pragma unroll
        for (int k = 0; k < PF3; ++k) {
            float cur = buf[k];
            float p0 = 0.f, p1 = 0.f, p2 = 0.f, p3 = 0.f;
            #pragma unroll
            for (int i = 0; i < 8; ++i) {
                x[4*i+0] = fmaf(A[4*i+0], x[4*i+0], cur);
                x[4*i+1] = fmaf(A[4*i+1], x[4*i+1], cur);
                x[4*i+2] = fmaf(A[4*i+2], x[4*i+2], cur);
                x[4*i+3] = fmaf(A[4*i+3], x[4*i+3], cur);
                p0 = fmaf(CB[4*i+0], x[4*i+0], p0);
                p1 = fmaf(CB[4*i+1], x[4*i+1], p1);
                p2 = fmaf(CB[4*i+2], x[4*i+2], p2);
                p3 = fmaf(CB[4*i+3], x[4*i+3], p3);
            }
            float s = (p0 + p1) + (p2 + p3);
            s += __shfl_xor(s, 1);              // pair (q=0,q=1) -> full 64-state sum
            *yp = __float2bfloat16(fmaf(Dh, cur, s));   // both lanes: same value, same addr
            yp += ostr;
        }
        if (blk < T_CH / PF3 - 1) {
            #pragma unroll
            for (int k = 0; k < PF3; ++k) buf[k] = nbuf[k];
        }
        up = nup;
    }
}

// ---------------- K4: out = ycat(bf16) @ W(bf16)^T + bias, f32 out ----------------
// A: [32768,1024] row-major, B: [512,1024] row-major (B^T GEMM), out: [32768,512]
// m97-style: global_load_lds width-16 staging into linear LDS tiles.
__global__ __launch_bounds__(256) void k_gemm(
    const __hip_bfloat16* __restrict__ A, const __hip_bfloat16* __restrict__ B,
    const float* __restrict__ bias, float* __restrict__ out)
{
    __shared__ __hip_bfloat16 As[128][32];
    __shared__ __hip_bfloat16 Bs[128][32];
    int t  = threadIdx.x;
    int l  = t & 63, w = t >> 6;
    int lr = l & 15, lg = l >> 4;
    int mBase = blockIdx.y * 128;
    int nBase = blockIdx.x * 128;
    int wr = (w >> 1) * 64, wc = (w & 1) * 64;

    // staging geometry: each thread DMAs one 16B chunk per issue, 2 issues per tile.
    // seg = i*256 + t covers linear halves; row = seg>>2, col8 = (seg&3)*8
    int rowL = w * 16 + (l >> 2);       // i=0 row (add 64 for i=1)
    int kb   = (l & 3) * 8;

    f32x4 acc[4][4] = {};

    for (int kt = 0; kt < K_GEMM; kt += 32) {
        __syncthreads();
        {
            const __hip_bfloat16* ga0 = A + (size_t)(mBase + rowL) * K_GEMM + kt + kb;
            const __hip_bfloat16* ga1 = A + (size_t)(mBase + 64 + rowL) * K_GEMM + kt + kb;
            const __hip_bfloat16* gb0 = B + (size_t)(nBase + rowL) * K_GEMM + kt + kb;
            const __hip_bfloat16* gb1 = B + (size_t)(nBase + 64 + rowL) * K_GEMM + kt + kb;
            char* la0 = ((char*)&As[0][0]) + (w * 64) * 16;
            char* la1 = ((char*)&As[0][0]) + (256 + w * 64) * 16;
            char* lb0 = ((char*)&Bs[0][0]) + (w * 64) * 16;
            char* lb1 = ((char*)&Bs[0][0]) + (256 + w * 64) * 16;
            __builtin_amdgcn_global_load_lds(
                (const __attribute__((address_space(1))) void*)ga0,
                (__attribute__((address_space(3))) void*)la0, 16, 0, 0);
            __builtin_amdgcn_global_load_lds(
                (const __attribute__((address_space(1))) void*)ga1,
                (__attribute__((address_space(3))) void*)la1, 16, 0, 0);
            __builtin_amdgcn_global_load_lds(
                (const __attribute__((address_space(1))) void*)gb0,
                (__attribute__((address_space(3))) void*)lb0, 16, 0, 0);
            __builtin_amdgcn_global_load_lds(
                (const __attribute__((address_space(1))) void*)gb1,
                (__attribute__((address_space(3))) void*)lb1, 16, 0, 0);
        }
        __syncthreads();
        bf16x8 af[4], bfv[4];
        #pragma unroll
        for (int m = 0; m < 4; ++m) af[m]  = *(const bf16x8*)&As[wr + m * 16 + lr][lg * 8];
        #pragma unroll
        for (int n = 0; n < 4; ++n) bfv[n] = *(const bf16x8*)&Bs[wc + n * 16 + lr][lg * 8];
        #pragma unroll
        for (int m = 0; m < 4; ++m)
            #pragma unroll
            for (int n = 0; n < 4; ++n)
                acc[m][n] = __builtin_amdgcn_mfma_f32_16x16x32_bf16(af[m], bfv[n], acc[m][n], 0, 0, 0);
    }

    #pragma unroll
    for (int n = 0; n < 4; ++n) {
        int colg = nBase + wc + n * 16 + lr;
        float bv = bias[colg];
        #pragma unroll
        for (int m = 0; m < 4; ++m) {
            int rowg = mBase + wr + m * 16 + lg * 4;
            #pragma unroll
            for (int r = 0; r < 4; ++r)
                out[(size_t)(rowg + r) * H_DIM + colg] = acc[m][n][r] + bv;
        }
    }
}

extern "C" void kernel_launch(void* const* d_in, const int* in_sizes, int n_in,
                              void* d_out, int out_size, void* d_ws, size_t ws_size,
                              hipStream_t stream)
{
    const float* u       = (const float*)d_in[0];
    const float* A_log   = (const float*)d_in[1];
    const float* Bv      = (const float*)d_in[2];
    const float* C       = (const float*)d_in[3];
    const float* D       = (const float*)d_in[4];
    const float* log_dt  = (const float*)d_in[5];
    const float* A_log_r = (const float*)d_in[6];
    const float* B_r     = (const float*)d_in[7];
    const float* C_r     = (const float*)d_in[8];
    const float* W_bi    = (const float*)d_in[9];
    const float* b_bi    = (const float*)d_in[10];
    float* out = (float*)d_out;

    char* ws = (char*)d_ws;
    float* pA  = (float*)(ws);                       // 65536 f
    float* pCB = (float*)(ws + 262144);              // 65536 f
    float* pPW = (float*)(ws + 524288);              // 65536 f
    float* S   = (float*)(ws + 786432);              // 8388608 f (32 MB)
    __hip_bfloat16* yc  = (__hip_bfloat16*)(ws + 786432 + 33554432);            // 64 MB
    __hip_bfloat16* Wbf = (__hip_bfloat16*)(ws + 786432 + 33554432 + 67108864); // 1 MB

    k_precompute<<<256,  256, 0, stream>>>(A_log, Bv, C, log_dt, A_log_r, B_r, C_r, pA, pCB, pPW);
    k_convw     <<<2048, 256, 0, stream>>>(W_bi, Wbf);
    k_chunkstate<<<1024, 256, 0, stream>>>(u, pA, S);
    k_chunkscan <<<2048, 256, 0, stream>>>(pPW, S);
    k_scanout   <<<1024, 256, 0, stream>>>(u, pA, pCB, D, S, yc);
    dim3 g(4, 256);
    k_gemm<<<g, 256, 0, stream>>>(yc, Wbf, b_bi, out);
}